// Round 14
// baseline (639.795 us; speedup 1.0000x reference)
//
#include <hip/hip_runtime.h>
#include <math.h>

#define NTOK   256000
#define TOKB   16000
#define EPS    1e-5f

__device__ __forceinline__ float gelu_f(float x){
  return 0.5f*x*(1.0f+erff(x*0.70710678118654752440f));
}
__device__ __forceinline__ float elu1_f(float x){
  return x>0.0f ? x+1.0f : __expf(x);   // elu(x)+1
}

// ---------------------------------------------------------------------------
// Tokenizer: band conv(51) -> 1x1 conv(4->32) -> BN -> GELU -> avgpool(4)
// ---------------------------------------------------------------------------
__global__ __launch_bounds__(256) void k_tokenize(
    const float* __restrict__ x, const float* __restrict__ band_w,
    const float* __restrict__ pw_w, const float* __restrict__ bn_g,
    const float* __restrict__ bn_b, const float* __restrict__ bn_m,
    const float* __restrict__ bn_v, float* __restrict__ hout)
{
  __shared__ float sx[1050];
  __shared__ float sbw[4][51];
  __shared__ float spw[32][4];
  __shared__ float sscale[32], sshift[32];
  const int tid = threadIdx.x;
  const int b = blockIdx.x >> 6, e = blockIdx.x & 63;
  const float* xr = x + (size_t)(b*64 + e)*1000;
  for (int i=tid;i<1050;i+=256){ int t=i-25; sx[i]=(t>=0&&t<1000)?xr[t]:0.0f; }
  for (int i=tid;i<204;i+=256){ sbw[i/51][i%51] = band_w[i]; }
  for (int i=tid;i<128;i+=256){ spw[i>>2][i&3] = pw_w[i]; }
  if (tid<32){ float sc = bn_g[tid]*rsqrtf(bn_v[tid]+EPS);
               sscale[tid]=sc; sshift[tid]=bn_b[tid]-bn_m[tid]*sc; }
  __syncthreads();
  const int tp = tid;
  if (tp < 250) {
    float acc[32];
    #pragma unroll
    for (int o=0;o<32;o++) acc[o]=0.0f;
    for (int j=0;j<4;j++){
      const int t = 4*tp+j;
      float c0=0,c1=0,c2=0,c3=0;
      for (int k=0;k<51;k++){
        float xv = sx[t+k];
        c0 += xv*sbw[0][k]; c1 += xv*sbw[1][k];
        c2 += xv*sbw[2][k]; c3 += xv*sbw[3][k];
      }
      #pragma unroll
      for (int o=0;o<32;o++){
        float hv = spw[o][0]*c0 + spw[o][1]*c1 + spw[o][2]*c2 + spw[o][3]*c3;
        hv = hv*sscale[o] + sshift[o];
        acc[o] += gelu_f(hv);
      }
    }
    const int tok = b*TOKB + e*250 + tp;
    float4* dst = (float4*)(hout + (size_t)tok*32);
    #pragma unroll
    for (int o8=0;o8<8;o8++)
      dst[o8] = make_float4(acc[o8*4]*0.25f, acc[o8*4+1]*0.25f,
                            acc[o8*4+2]*0.25f, acc[o8*4+3]*0.25f);
  }
}

// ---------------------------------------------------------------------------
// Pass A: per 128-token tile: ln1 -> k,v -> K-features -> partial KV[h,f,d]
// (R7 proven version)
// ---------------------------------------------------------------------------
__global__ __launch_bounds__(256) void k_kv_partial(
    const float* __restrict__ hbuf, const float* __restrict__ ln1_g,
    const float* __restrict__ ln1_b, const float* __restrict__ wqkv,
    const float* __restrict__ proj_mat, float* __restrict__ kvpart, int l)
{
  __shared__ __align__(16) float sk[128][36];
  __shared__ __align__(16) float sv[128][36];
  __shared__ __align__(16) float swkT[64][32];
  __shared__ float sg[32], sb[32];
  const int tid = threadIdx.x;
  const float* W = wqkv + l*32*96;
  for (int idx=tid;idx<2048;idx+=256){
    int i = idx&31, j = idx>>5;
    swkT[j][i] = W[i*96 + 32 + j];
  }
  if (tid<32){ sg[tid]=ln1_g[l*32+tid]; sb[tid]=ln1_b[l*32+tid]; }
  __syncthreads();
  {
    const int tloc = tid>>1, half = tid&1;
    const int tok = blockIdx.x*128 + tloc;
    float hx[32];
    const float4* src = (const float4*)(hbuf + (size_t)tok*32);
    #pragma unroll
    for (int i=0;i<8;i++){ float4 v4=src[i]; hx[4*i]=v4.x; hx[4*i+1]=v4.y; hx[4*i+2]=v4.z; hx[4*i+3]=v4.w; }
    float mu=0;
    #pragma unroll
    for (int i=0;i<32;i++) mu += hx[i];
    mu *= (1.0f/32.0f);
    float vs=0;
    #pragma unroll
    for (int i=0;i<32;i++){ float d=hx[i]-mu; vs += d*d; }
    const float inv = rsqrtf(vs*(1.0f/32.0f)+EPS);
    float xn[32];
    #pragma unroll
    for (int i=0;i<32;i++) xn[i] = (hx[i]-mu)*inv*sg[i]+sb[i];
    const int j0 = half*16;
    #pragma unroll 4
    for (int jj=0;jj<16;jj++){
      const int j = j0+jj;
      const float4* wk4 = (const float4*)&swkT[j][0];
      const float4* wv4 = (const float4*)&swkT[32+j][0];
      float ka=0, va=0;
      #pragma unroll
      for (int i4=0;i4<8;i4++){
        float4 wk = wk4[i4], wv = wv4[i4];
        ka += xn[4*i4+0]*wk.x + xn[4*i4+1]*wk.y + xn[4*i4+2]*wk.z + xn[4*i4+3]*wk.w;
        va += xn[4*i4+0]*wv.x + xn[4*i4+1]*wv.y + xn[4*i4+2]*wv.z + xn[4*i4+3]*wv.w;
      }
      sk[tloc][j]=ka; sv[tloc][j]=va;
    }
  }
  __syncthreads();
  const int hh = tid>>6, f = tid&63;
  float pm0,pm1,pm2,pm3,pm4,pm5,pm6,pm7;
  {
    const float* pmp = proj_mat + ((size_t)(l*4+hh)*8)*64 + f;
    pm0=pmp[0]; pm1=pmp[64]; pm2=pmp[128]; pm3=pmp[192];
    pm4=pmp[256]; pm5=pmp[320]; pm6=pmp[384]; pm7=pmp[448];
  }
  float a0=0,a1=0,a2=0,a3=0,a4=0,a5=0,a6=0,a7=0;
  #pragma unroll 4
  for (int t=0;t<128;t++){
    const float4* k4 = (const float4*)&sk[t][hh*8];
    const float4* v4 = (const float4*)&sv[t][hh*8];
    float4 ka = k4[0], kb = k4[1];
    float kd = ka.x*pm0 + ka.y*pm1 + ka.z*pm2 + ka.w*pm3
             + kb.x*pm4 + kb.y*pm5 + kb.z*pm6 + kb.w*pm7;
    const float Kf = elu1_f(kd);
    float4 va = v4[0], vb = v4[1];
    a0 += Kf*va.x; a1 += Kf*va.y; a2 += Kf*va.z; a3 += Kf*va.w;
    a4 += Kf*vb.x; a5 += Kf*vb.y; a6 += Kf*vb.z; a7 += Kf*vb.w;
  }
  float4* dst = (float4*)(kvpart + (size_t)blockIdx.x*2048 + tid*8);
  dst[0] = make_float4(a0,a1,a2,a3);
  dst[1] = make_float4(a4,a5,a6,a7);
}

// fixed-order hierarchical KV reduction: 2000 partials -> 10 chunks -> final
__global__ __launch_bounds__(256) void k_kv_reduce1(
    const float* __restrict__ kvpart, float* __restrict__ p2)
{
  const int chunk = blockIdx.x >> 3;
  const int e = (blockIdx.x&7)*256 + threadIdx.x;
  float acc=0.0f;
  const int base = chunk*200;
  for (int ab=0; ab<200; ab++) acc += kvpart[(size_t)(base+ab)*2048 + e];
  p2[chunk*2048 + e] = acc;
}

__global__ __launch_bounds__(256) void k_kv_reduce2(
    const float* __restrict__ p2, float* __restrict__ KV)
{
  const int hf = threadIdx.x;
  float acc[8];
  #pragma unroll
  for (int d=0;d<8;d++) acc[d]=0.0f;
  for (int c=0;c<10;c++){
    #pragma unroll
    for (int d=0;d<8;d++) acc[d] += p2[c*2048 + hf*8 + d];
  }
  #pragma unroll
  for (int d=0;d<8;d++) KV[hf*8+d]=acc[d];
}

// ---------------------------------------------------------------------------
// Pass C1 (R7 proven, T=1 thread-per-token): ln1 -> per-head q,Qfeat,attn ->
// proj+residual. All weight reads are wave-uniform LDS broadcasts; no
// shuffles or barriers in hot path; every register array statically indexed.
// 116 us / dispatch, VGPR 68, zero scratch. T=2 variants (R10-R13) all
// spilled -- line closed.
// ---------------------------------------------------------------------------
__global__ __launch_bounds__(256) void k_attn(
    float* __restrict__ hbuf,
    const float* __restrict__ ln1_g, const float* __restrict__ ln1_b,
    const float* __restrict__ wqkv, const float* __restrict__ proj_mat,
    const float* __restrict__ wproj, const float* __restrict__ bproj,
    const float* __restrict__ KV, int l)
{
  __shared__ __align__(16) float swqT[32][32];     // [j][i] = wqkv[i][j]
  __shared__ __align__(16) float pmT[4][64][8];    // [h][f][d]
  __shared__ __align__(16) float kvT[4][64][8];    // [h][f][d]
  __shared__ __align__(16) float wpT[32][32];      // [o][i] = wproj[i][o]
  __shared__ float s1g[32],s1b[32],sbp[32];
  const int tid = threadIdx.x;
  for (int idx=tid;idx<1024;idx+=256){
    int j=idx>>5, i=idx&31;
    swqT[j][i] = wqkv[l*3072 + i*96 + j];
    wpT[j][i]  = wproj[l*1024 + i*32 + j];
  }
  for (int idx=tid;idx<2048;idx+=256){
    int hh=idx>>9, f=(idx>>3)&63, d=idx&7;
    pmT[hh][f][d] = proj_mat[l*2048 + hh*512 + d*64 + f];
    (&kvT[0][0][0])[idx] = KV[idx];
  }
  if (tid<32){ s1g[tid]=ln1_g[l*32+tid]; s1b[tid]=ln1_b[l*32+tid];
               sbp[tid]=bproj[l*32+tid]; }
  __syncthreads();

  const int tok = blockIdx.x*256 + tid;
  float4* hp = (float4*)(hbuf + (size_t)tok*32);

  // ---- ln1 (lane-local) ----
  float xn[32];
  {
    float hx[32];
    #pragma unroll
    for (int i=0;i<8;i++){ float4 v=hp[i]; hx[4*i]=v.x; hx[4*i+1]=v.y; hx[4*i+2]=v.z; hx[4*i+3]=v.w; }
    float mu=0;
    #pragma unroll
    for (int i=0;i<32;i++) mu += hx[i];
    mu *= (1.0f/32.0f);
    float vs=0;
    #pragma unroll
    for (int i=0;i<32;i++){ float d=hx[i]-mu; vs += d*d; }
    const float inv = rsqrtf(vs*(1.0f/32.0f)+EPS);
    #pragma unroll
    for (int i=0;i<32;i++) xn[i] = (hx[i]-mu)*inv*s1g[i]+s1b[i];
  }

  // ---- per-head: q slice -> Qfeat stream -> normalized att ----
  float att[32];
  #pragma unroll
  for (int hh=0;hh<4;hh++){
    float qh[8];
    #pragma unroll
    for (int d=0;d<8;d++){
      const float4* wr = (const float4*)&swqT[hh*8+d][0];
      float a=0;
      #pragma unroll
      for (int i4=0;i4<8;i4++){
        float4 w = wr[i4];
        a += xn[4*i4+0]*w.x + xn[4*i4+1]*w.y + xn[4*i4+2]*w.z + xn[4*i4+3]*w.w;
      }
      qh[d]=a;
    }
    float ao[8];
    #pragma unroll
    for (int d=0;d<8;d++) ao[d]=0.0f;
    for (int f=0;f<64;f++){
      const float4* pm4 = (const float4*)&pmT[hh][f][0];
      float4 pa = pm4[0], pb = pm4[1];
      float qd = qh[0]*pa.x+qh[1]*pa.y+qh[2]*pa.z+qh[3]*pa.w
               + qh[4]*pb.x+qh[5]*pb.y+qh[6]*pb.z+qh[7]*pb.w;
      const float Qf = elu1_f(qd);
      const float4* kv4 = (const float4*)&kvT[hh][f][0];
      float4 va = kv4[0], vb = kv4[1];
      ao[0] += Qf*va.x; ao[1] += Qf*va.y; ao[2] += Qf*va.z; ao[3] += Qf*va.w;
      ao[4] += Qf*vb.x; ao[5] += Qf*vb.y; ao[6] += Qf*vb.z; ao[7] += Qf*vb.w;
    }
    const float den = ao[0]+ao[1]+ao[2]+ao[3]+ao[4]+ao[5]+ao[6]+ao[7];
    const float z = 1.0f/den;
    #pragma unroll
    for (int d=0;d<8;d++) att[hh*8+d] = ao[d]*z;
  }

  // ---- proj + residual, streamed in float4 output chunks ----
  const float4* sbp4 = (const float4*)sbp;
  for (int o4=0;o4<8;o4++){
    float4 bb = sbp4[o4];
    float p0=bb.x, p1=bb.y, p2=bb.z, p3=bb.w;
    const float4* w0 = (const float4*)&wpT[o4*4+0][0];
    const float4* w1r= (const float4*)&wpT[o4*4+1][0];
    const float4* w2r= (const float4*)&wpT[o4*4+2][0];
    const float4* w3 = (const float4*)&wpT[o4*4+3][0];
    #pragma unroll
    for (int i4=0;i4<8;i4++){
      float4 a0=w0[i4], a1=w1r[i4], a2=w2r[i4], a3=w3[i4];
      p0 += att[4*i4+0]*a0.x + att[4*i4+1]*a0.y + att[4*i4+2]*a0.z + att[4*i4+3]*a0.w;
      p1 += att[4*i4+0]*a1.x + att[4*i4+1]*a1.y + att[4*i4+2]*a1.z + att[4*i4+3]*a1.w;
      p2 += att[4*i4+0]*a2.x + att[4*i4+1]*a2.y + att[4*i4+2]*a2.z + att[4*i4+3]*a2.w;
      p3 += att[4*i4+0]*a3.x + att[4*i4+1]*a3.y + att[4*i4+2]*a3.z + att[4*i4+3]*a3.w;
    }
    float4 hx4 = hp[o4];
    hp[o4] = make_float4(hx4.x+p0, hx4.y+p1, hx4.z+p2, hx4.w+p3);
  }
}

// ---------------------------------------------------------------------------
// Pass C2: thread handles TWO tokens (R10/R12/R13, proven). ln2 -> FFN -> res.
// ---------------------------------------------------------------------------
__global__ __launch_bounds__(256) void k_ffn(
    float* __restrict__ hbuf,
    const float* __restrict__ ln2_g, const float* __restrict__ ln2_b,
    const float* __restrict__ w1, const float* __restrict__ b1,
    const float* __restrict__ w2, const float* __restrict__ b2, int l)
{
  __shared__ __align__(16) float w1T[64][32];   // [j][i]
  __shared__ __align__(16) float sw2[64][32];   // [j][c]
  __shared__ float s2g[32],s2b[32],sb1[64],sb2[32];
  const int tid = threadIdx.x;
  for (int idx=tid;idx<2048;idx+=256){
    int j=idx>>5, i=idx&31;
    w1T[j][i] = w1[l*2048 + i*64 + j];
    (&sw2[0][0])[idx] = w2[l*2048 + idx];
  }
  if (tid<32){ s2g[tid]=ln2_g[l*32+tid]; s2b[tid]=ln2_b[l*32+tid];
               sb2[tid]=b2[l*32+tid]; }
  if (tid<64) sb1[tid]=b1[l*64+tid];
  __syncthreads();

  const int tok0 = blockIdx.x*512 + tid;
  float4* hpA = (float4*)(hbuf + (size_t)tok0*32);
  float4* hpB = hpA + 256*8;

  float mA[32], mB[32];
  {
    float hx[32];
    #pragma unroll
    for (int i=0;i<8;i++){ float4 v=hpA[i]; hx[4*i]=v.x; hx[4*i+1]=v.y; hx[4*i+2]=v.z; hx[4*i+3]=v.w; }
    float mu=0;
    #pragma unroll
    for (int i=0;i<32;i++) mu += hx[i];
    mu *= (1.0f/32.0f);
    float vs=0;
    #pragma unroll
    for (int i=0;i<32;i++){ float d=hx[i]-mu; vs += d*d; }
    const float inv = rsqrtf(vs*(1.0f/32.0f)+EPS);
    #pragma unroll
    for (int i=0;i<32;i++) mA[i] = (hx[i]-mu)*inv*s2g[i]+s2b[i];
  }
  {
    float hx[32];
    #pragma unroll
    for (int i=0;i<8;i++){ float4 v=hpB[i]; hx[4*i]=v.x; hx[4*i+1]=v.y; hx[4*i+2]=v.z; hx[4*i+3]=v.w; }
    float mu=0;
    #pragma unroll
    for (int i=0;i<32;i++) mu += hx[i];
    mu *= (1.0f/32.0f);
    float vs=0;
    #pragma unroll
    for (int i=0;i<32;i++){ float d=hx[i]-mu; vs += d*d; }
    const float inv = rsqrtf(vs*(1.0f/32.0f)+EPS);
    #pragma unroll
    for (int i=0;i<32;i++) mB[i] = (hx[i]-mu)*inv*s2g[i]+s2b[i];
  }

  float fA[32], fB[32];
  #pragma unroll
  for (int c=0;c<32;c++){ fA[c]=sb2[c]; fB[c]=sb2[c]; }

  #pragma unroll 2
  for (int j=0;j<64;j++){
    const float4* r1 = (const float4*)&w1T[j][0];
    float gA = sb1[j], gB = sb1[j];
    #pragma unroll
    for (int i4=0;i4<8;i4++){
      float4 w = r1[i4];
      gA += mA[4*i4+0]*w.x + mA[4*i4+1]*w.y + mA[4*i4+2]*w.z + mA[4*i4+3]*w.w;
      gB += mB[4*i4+0]*w.x + mB[4*i4+1]*w.y + mB[4*i4+2]*w.z + mB[4*i4+3]*w.w;
    }
    const float ggA = gelu_f(gA);
    const float ggB = gelu_f(gB);
    const float4* r2 = (const float4*)&sw2[j][0];
    #pragma unroll
    for (int c4=0;c4<8;c4++){
      float4 w = r2[c4];
      fA[4*c4+0] += ggA*w.x; fA[4*c4+1] += ggA*w.y; fA[4*c4+2] += ggA*w.z; fA[4*c4+3] += ggA*w.w;
      fB[4*c4+0] += ggB*w.x; fB[4*c4+1] += ggB*w.y; fB[4*c4+2] += ggB*w.z; fB[4*c4+3] += ggB*w.w;
    }
  }

  #pragma unroll
  for (int o4=0;o4<8;o4++){
    float4 hA = hpA[o4];
    hpA[o4] = make_float4(hA.x+fA[4*o4+0], hA.y+fA[4*o4+1],
                          hA.z+fA[4*o4+2], hA.w+fA[4*o4+3]);
    float4 hB = hpB[o4];
    hpB[o4] = make_float4(hB.x+fB[4*o4+0], hB.y+fB[4*o4+1],
                          hB.z+fB[4*o4+2], hB.w+fB[4*o4+3]);
  }
}

// ---------------------------------------------------------------------------
// Final: layernorm -> pool score s; softmax over N per batch; weighted sum; fc
// ---------------------------------------------------------------------------
__global__ __launch_bounds__(256) void k_pool_score(
    const float* __restrict__ hbuf, const float* __restrict__ ng,
    const float* __restrict__ nb, const float* __restrict__ pw,
    const float* __restrict__ pb, float* __restrict__ s)
{
  const int tok = blockIdx.x*256 + threadIdx.x;
  float hx[32];
  const float4* src = (const float4*)(hbuf + (size_t)tok*32);
  #pragma unroll
  for (int i=0;i<8;i++){ float4 v4=src[i]; hx[4*i]=v4.x; hx[4*i+1]=v4.y; hx[4*i+2]=v4.z; hx[4*i+3]=v4.w; }
  float mu=0;
  #pragma unroll
  for (int i=0;i<32;i++) mu += hx[i];
  mu *= (1.0f/32.0f);
  float vs=0;
  #pragma unroll
  for (int i=0;i<32;i++){ float d=hx[i]-mu; vs += d*d; }
  const float inv = rsqrtf(vs*(1.0f/32.0f)+EPS);
  float sv = pb[0];
  #pragma unroll
  for (int i=0;i<32;i++) sv += ((hx[i]-mu)*inv*ng[i]+nb[i])*pw[i];
  s[tok]=sv;
}

__global__ __launch_bounds__(256) void k_softmax_stats(
    const float* __restrict__ s, float* __restrict__ bmax, float* __restrict__ bsum)
{
  __shared__ float red[256];
  __shared__ float smax_sh;
  const int b = blockIdx.x, tid = threadIdx.x;
  const float* sbp = s + (size_t)b*TOKB;
  float mx = -INFINITY;
  for (int i=tid;i<TOKB;i+=256) mx = fmaxf(mx, sbp[i]);
  red[tid]=mx; __syncthreads();
  for (int st=128;st>0;st>>=1){ if(tid<st) red[tid]=fmaxf(red[tid],red[tid+st]); __syncthreads(); }
  if (tid==0) smax_sh = red[0];
  __syncthreads();
  const float smax = smax_sh;
  float acc=0.0f;
  for (int i=tid;i<TOKB;i+=256) acc += __expf(sbp[i]-smax);
  __syncthreads();
  red[tid]=acc; __syncthreads();
  for (int st=128;st>0;st>>=1){ if(tid<st) red[tid]+=red[tid+st]; __syncthreads(); }
  if (tid==0){ bmax[b]=smax; bsum[b]=red[0]; }
}

__global__ __launch_bounds__(256) void k_pool_partial(
    const float* __restrict__ hbuf, const float* __restrict__ ng,
    const float* __restrict__ nb, const float* __restrict__ s,
    const float* __restrict__ bmax, float* __restrict__ pp)
{
  __shared__ float red[256][33];
  const int b = blockIdx.x/63, ch = blockIdx.x%63;
  const int tid = threadIdx.x;
  const int n = ch*256+tid;
  if (n < TOKB) {
    const int tok = b*TOKB+n;
    float hx[32];
    const float4* src = (const float4*)(hbuf + (size_t)tok*32);
    #pragma unroll
    for (int i=0;i<8;i++){ float4 v4=src[i]; hx[4*i]=v4.x; hx[4*i+1]=v4.y; hx[4*i+2]=v4.z; hx[4*i+3]=v4.w; }
    float mu=0;
    #pragma unroll
    for (int i=0;i<32;i++) mu += hx[i];
    mu *= (1.0f/32.0f);
    float vs=0;
    #pragma unroll
    for (int i=0;i<32;i++){ float d=hx[i]-mu; vs += d*d; }
    const float inv = rsqrtf(vs*(1.0f/32.0f)+EPS);
    const float w = __expf(s[tok]-bmax[b]);
    #pragma unroll
    for (int i=0;i<32;i++) red[tid][i] = w*((hx[i]-mu)*inv*ng[i]+nb[i]);
  } else {
    #pragma unroll
    for (int i=0;i<32;i++) red[tid][i]=0.0f;
  }
  __syncthreads();
  if (tid<32){
    float acc=0.0f;
    for (int t=0;t<256;t++) acc += red[t][tid];
    pp[(size_t)blockIdx.x*32 + tid] = acc;
  }
}

__global__ __launch_bounds__(64) void k_pool_final(
    const float* __restrict__ pp, const float* __restrict__ bsum,
    const float* __restrict__ fcw, const float* __restrict__ fcb,
    float* __restrict__ out)
{
  __shared__ float sp[32];
  const int b = blockIdx.x, tid = threadIdx.x;
  if (tid<32){
    float acc=0.0f;
    for (int ch=0;ch<63;ch++) acc += pp[(size_t)(b*63+ch)*32+tid];
    sp[tid] = acc / bsum[b];
  }
  __syncthreads();
  if (tid<2){
    float v = fcb[tid];
    for (int o=0;o<32;o++) v += sp[o]*fcw[o*2+tid];
    out[b*2+tid]=v;
  }
}

extern "C" void kernel_launch(void* const* d_in, const int* in_sizes, int n_in,
                              void* d_out, int out_size, void* d_ws, size_t ws_size,
                              hipStream_t stream)
{
  const float* x      = (const float*)d_in[0];
  const float* band_w = (const float*)d_in[1];
  const float* pw_w   = (const float*)d_in[2];
  const float* bn_g   = (const float*)d_in[3];
  const float* bn_b   = (const float*)d_in[4];
  const float* bn_m   = (const float*)d_in[5];
  const float* bn_v   = (const float*)d_in[6];
  const float* ln1_g  = (const float*)d_in[7];
  const float* ln1_b  = (const float*)d_in[8];
  const float* wqkv   = (const float*)d_in[9];
  const float* proj   = (const float*)d_in[10];
  const float* wproj  = (const float*)d_in[11];
  const float* bprojp = (const float*)d_in[12];
  const float* ln2_g  = (const float*)d_in[13];
  const float* ln2_b  = (const float*)d_in[14];
  const float* w1     = (const float*)d_in[15];
  const float* b1     = (const float*)d_in[16];
  const float* w2     = (const float*)d_in[17];
  const float* b2     = (const float*)d_in[18];
  const float* norm_g = (const float*)d_in[19];
  const float* norm_b = (const float*)d_in[20];
  const float* pool_w = (const float*)d_in[21];
  const float* pool_b = (const float*)d_in[22];
  const float* fc_w   = (const float*)d_in[23];
  const float* fc_b   = (const float*)d_in[24];
  float* out = (float*)d_out;
  float* ws  = (float*)d_ws;

  float* hbuf  = ws;                       // 8,192,000 floats (32 MB)
  float* kvp   = hbuf + 8192000;           // 2000*2048 = 4,096,000
  float* p2    = kvp  + 4096000;           // 10*2048 = 20,480
  float* KV    = p2   + 20480;             // 2048
  float* sbuf  = KV   + 2048;              // 256,000
  float* bmax  = sbuf + 256000;            // 16
  float* bsum  = bmax + 16;                // 16
  float* pp    = bsum + 16;                // 16*63*32 = 32,256

  k_tokenize<<<1024,256,0,stream>>>(x, band_w, pw_w, bn_g, bn_b, bn_m, bn_v, hbuf);
  for (int l=0;l<2;l++){
    k_kv_partial<<<2000,256,0,stream>>>(hbuf, ln1_g, ln1_b, wqkv, proj, kvp, l);
    k_kv_reduce1<<<80,256,0,stream>>>(kvp, p2);
    k_kv_reduce2<<<1,256,0,stream>>>(p2, KV);
    k_attn<<<1000,256,0,stream>>>(hbuf, ln1_g, ln1_b, wqkv, proj, wproj, bprojp, KV, l);
    k_ffn<<<500,256,0,stream>>>(hbuf, ln2_g, ln2_b, w1, b1, w2, b2, l);
  }
  k_pool_score<<<1000,256,0,stream>>>(hbuf, norm_g, norm_b, pool_w, pool_b, sbuf);
  k_softmax_stats<<<16,256,0,stream>>>(sbuf, bmax, bsum);
  k_pool_partial<<<16*63,256,0,stream>>>(hbuf, norm_g, norm_b, sbuf, bmax, pp);
  k_pool_final<<<16,64,0,stream>>>(pp, bsum, fc_w, fc_b, out);
}

// Round 16
// 631.374 us; speedup vs baseline: 1.0133x; 1.0133x over previous
//
#include <hip/hip_runtime.h>
#include <math.h>

#define NTOK   256000
#define TOKB   16000
#define EPS    1e-5f

typedef _Float16 h2 __attribute__((ext_vector_type(2)));

__device__ __forceinline__ float gelu_f(float x){
  return 0.5f*x*(1.0f+erff(x*0.70710678118654752440f));
}
__device__ __forceinline__ float elu1_f(float x){
  return x>0.0f ? x+1.0f : __expf(x);   // elu(x)+1
}
// packed-f16 helpers: one uint = 2 weights; fd2 = v_dot2_f32_f16
__device__ __forceinline__ unsigned pk2(float a, float b){
  union { unsigned u; h2 h; } x; x.h.x=(_Float16)a; x.h.y=(_Float16)b; return x.u;
}
__device__ __forceinline__ float fd2(unsigned w, h2 a, float c){
  union { unsigned u; h2 h; } x; x.u=w;
  return __builtin_amdgcn_fdot2(x.h, a, c, false);
}
__device__ __forceinline__ float2 up2(unsigned u){
  union { unsigned u; h2 h; } x; x.u=u;
  return make_float2((float)x.h.x, (float)x.h.y);
}

// ---------------------------------------------------------------------------
// Tokenizer: band conv(51) -> 1x1 conv(4->32) -> BN -> GELU -> avgpool(4)
// ---------------------------------------------------------------------------
__global__ __launch_bounds__(256) void k_tokenize(
    const float* __restrict__ x, const float* __restrict__ band_w,
    const float* __restrict__ pw_w, const float* __restrict__ bn_g,
    const float* __restrict__ bn_b, const float* __restrict__ bn_m,
    const float* __restrict__ bn_v, float* __restrict__ hout)
{
  __shared__ float sx[1050];
  __shared__ float sbw[4][51];
  __shared__ float spw[32][4];
  __shared__ float sscale[32], sshift[32];
  const int tid = threadIdx.x;
  const int b = blockIdx.x >> 6, e = blockIdx.x & 63;
  const float* xr = x + (size_t)(b*64 + e)*1000;
  for (int i=tid;i<1050;i+=256){ int t=i-25; sx[i]=(t>=0&&t<1000)?xr[t]:0.0f; }
  for (int i=tid;i<204;i+=256){ sbw[i/51][i%51] = band_w[i]; }
  for (int i=tid;i<128;i+=256){ spw[i>>2][i&3] = pw_w[i]; }
  if (tid<32){ float sc = bn_g[tid]*rsqrtf(bn_v[tid]+EPS);
               sscale[tid]=sc; sshift[tid]=bn_b[tid]-bn_m[tid]*sc; }
  __syncthreads();
  const int tp = tid;
  if (tp < 250) {
    float acc[32];
    #pragma unroll
    for (int o=0;o<32;o++) acc[o]=0.0f;
    for (int j=0;j<4;j++){
      const int t = 4*tp+j;
      float c0=0,c1=0,c2=0,c3=0;
      for (int k=0;k<51;k++){
        float xv = sx[t+k];
        c0 += xv*sbw[0][k]; c1 += xv*sbw[1][k];
        c2 += xv*sbw[2][k]; c3 += xv*sbw[3][k];
      }
      #pragma unroll
      for (int o=0;o<32;o++){
        float hv = spw[o][0]*c0 + spw[o][1]*c1 + spw[o][2]*c2 + spw[o][3]*c3;
        hv = hv*sscale[o] + sshift[o];
        acc[o] += gelu_f(hv);
      }
    }
    const int tok = b*TOKB + e*250 + tp;
    float4* dst = (float4*)(hout + (size_t)tok*32);
    #pragma unroll
    for (int o8=0;o8<8;o8++)
      dst[o8] = make_float4(acc[o8*4]*0.25f, acc[o8*4+1]*0.25f,
                            acc[o8*4+2]*0.25f, acc[o8*4+3]*0.25f);
  }
}

// ---------------------------------------------------------------------------
// Pass A: per 128-token tile: ln1 -> k,v -> K-features -> partial KV[h,f,d]
// (R7/R14 proven fp32 version)
// ---------------------------------------------------------------------------
__global__ __launch_bounds__(256) void k_kv_partial(
    const float* __restrict__ hbuf, const float* __restrict__ ln1_g,
    const float* __restrict__ ln1_b, const float* __restrict__ wqkv,
    const float* __restrict__ proj_mat, float* __restrict__ kvpart, int l)
{
  __shared__ __align__(16) float sk[128][36];
  __shared__ __align__(16) float sv[128][36];
  __shared__ __align__(16) float swkT[64][32];
  __shared__ float sg[32], sb[32];
  const int tid = threadIdx.x;
  const float* W = wqkv + l*32*96;
  for (int idx=tid;idx<2048;idx+=256){
    int i = idx&31, j = idx>>5;
    swkT[j][i] = W[i*96 + 32 + j];
  }
  if (tid<32){ sg[tid]=ln1_g[l*32+tid]; sb[tid]=ln1_b[l*32+tid]; }
  __syncthreads();
  {
    const int tloc = tid>>1, half = tid&1;
    const int tok = blockIdx.x*128 + tloc;
    float hx[32];
    const float4* src = (const float4*)(hbuf + (size_t)tok*32);
    #pragma unroll
    for (int i=0;i<8;i++){ float4 v4=src[i]; hx[4*i]=v4.x; hx[4*i+1]=v4.y; hx[4*i+2]=v4.z; hx[4*i+3]=v4.w; }
    float mu=0;
    #pragma unroll
    for (int i=0;i<32;i++) mu += hx[i];
    mu *= (1.0f/32.0f);
    float vs=0;
    #pragma unroll
    for (int i=0;i<32;i++){ float d=hx[i]-mu; vs += d*d; }
    const float inv = rsqrtf(vs*(1.0f/32.0f)+EPS);
    float xn[32];
    #pragma unroll
    for (int i=0;i<32;i++) xn[i] = (hx[i]-mu)*inv*sg[i]+sb[i];
    const int j0 = half*16;
    #pragma unroll 4
    for (int jj=0;jj<16;jj++){
      const int j = j0+jj;
      const float4* wk4 = (const float4*)&swkT[j][0];
      const float4* wv4 = (const float4*)&swkT[32+j][0];
      float ka=0, va=0;
      #pragma unroll
      for (int i4=0;i4<8;i4++){
        float4 wk = wk4[i4], wv = wv4[i4];
        ka += xn[4*i4+0]*wk.x + xn[4*i4+1]*wk.y + xn[4*i4+2]*wk.z + xn[4*i4+3]*wk.w;
        va += xn[4*i4+0]*wv.x + xn[4*i4+1]*wv.y + xn[4*i4+2]*wv.z + xn[4*i4+3]*wv.w;
      }
      sk[tloc][j]=ka; sv[tloc][j]=va;
    }
  }
  __syncthreads();
  const int hh = tid>>6, f = tid&63;
  float pm0,pm1,pm2,pm3,pm4,pm5,pm6,pm7;
  {
    const float* pmp = proj_mat + ((size_t)(l*4+hh)*8)*64 + f;
    pm0=pmp[0]; pm1=pmp[64]; pm2=pmp[128]; pm3=pmp[192];
    pm4=pmp[256]; pm5=pmp[320]; pm6=pmp[384]; pm7=pmp[448];
  }
  float a0=0,a1=0,a2=0,a3=0,a4=0,a5=0,a6=0,a7=0;
  #pragma unroll 4
  for (int t=0;t<128;t++){
    const float4* k4 = (const float4*)&sk[t][hh*8];
    const float4* v4 = (const float4*)&sv[t][hh*8];
    float4 ka = k4[0], kb = k4[1];
    float kd = ka.x*pm0 + ka.y*pm1 + ka.z*pm2 + ka.w*pm3
             + kb.x*pm4 + kb.y*pm5 + kb.z*pm6 + kb.w*pm7;
    const float Kf = elu1_f(kd);
    float4 va = v4[0], vb = v4[1];
    a0 += Kf*va.x; a1 += Kf*va.y; a2 += Kf*va.z; a3 += Kf*va.w;
    a4 += Kf*vb.x; a5 += Kf*vb.y; a6 += Kf*vb.z; a7 += Kf*vb.w;
  }
  float4* dst = (float4*)(kvpart + (size_t)blockIdx.x*2048 + tid*8);
  dst[0] = make_float4(a0,a1,a2,a3);
  dst[1] = make_float4(a4,a5,a6,a7);
}

// fixed-order hierarchical KV reduction: 2000 partials -> 10 chunks -> final
__global__ __launch_bounds__(256) void k_kv_reduce1(
    const float* __restrict__ kvpart, float* __restrict__ p2)
{
  const int chunk = blockIdx.x >> 3;
  const int e = (blockIdx.x&7)*256 + threadIdx.x;
  float acc=0.0f;
  const int base = chunk*200;
  for (int ab=0; ab<200; ab++) acc += kvpart[(size_t)(base+ab)*2048 + e];
  p2[chunk*2048 + e] = acc;
}

__global__ __launch_bounds__(256) void k_kv_reduce2(
    const float* __restrict__ p2, float* __restrict__ KV)
{
  const int hf = threadIdx.x;
  float acc[8];
  #pragma unroll
  for (int d=0;d<8;d++) acc[d]=0.0f;
  for (int c=0;c<10;c++){
    #pragma unroll
    for (int d=0;d<8;d++) acc[d] += p2[c*2048 + hf*8 + d];
  }
  #pragma unroll
  for (int d=0;d<8;d++) KV[hf*8+d]=acc[d];
}

// ---------------------------------------------------------------------------
// Pass C1 (R7/R14 proven fp32, T=1): ln1 -> q -> per-head attn -> proj+res.
// ---------------------------------------------------------------------------
__global__ __launch_bounds__(256) void k_attn(
    float* __restrict__ hbuf,
    const float* __restrict__ ln1_g, const float* __restrict__ ln1_b,
    const float* __restrict__ wqkv, const float* __restrict__ proj_mat,
    const float* __restrict__ wproj, const float* __restrict__ bproj,
    const float* __restrict__ KV, int l)
{
  __shared__ __align__(16) float swqT[32][32];     // [j][i]
  __shared__ __align__(16) float pmT[4][64][8];    // [h][f][d]
  __shared__ __align__(16) float kvT[4][64][8];    // [h][f][d]
  __shared__ __align__(16) float wpT[32][32];      // [o][i]
  __shared__ float s1g[32],s1b[32],sbp[32];
  const int tid = threadIdx.x;
  for (int idx=tid;idx<1024;idx+=256){
    int j=idx>>5, i=idx&31;
    swqT[j][i] = wqkv[l*3072 + i*96 + j];
    wpT[j][i]  = wproj[l*1024 + i*32 + j];
  }
  for (int idx=tid;idx<2048;idx+=256){
    int hh=idx>>9, f=(idx>>3)&63, d=idx&7;
    pmT[hh][f][d] = proj_mat[l*2048 + hh*512 + d*64 + f];
    (&kvT[0][0][0])[idx] = KV[idx];
  }
  if (tid<32){ s1g[tid]=ln1_g[l*32+tid]; s1b[tid]=ln1_b[l*32+tid];
               sbp[tid]=bproj[l*32+tid]; }
  __syncthreads();

  const int tok = blockIdx.x*256 + tid;
  float4* hp = (float4*)(hbuf + (size_t)tok*32);

  float xn[32];
  {
    float hx[32];
    #pragma unroll
    for (int i=0;i<8;i++){ float4 v=hp[i]; hx[4*i]=v.x; hx[4*i+1]=v.y; hx[4*i+2]=v.z; hx[4*i+3]=v.w; }
    float mu=0;
    #pragma unroll
    for (int i=0;i<32;i++) mu += hx[i];
    mu *= (1.0f/32.0f);
    float vs=0;
    #pragma unroll
    for (int i=0;i<32;i++){ float d=hx[i]-mu; vs += d*d; }
    const float inv = rsqrtf(vs*(1.0f/32.0f)+EPS);
    #pragma unroll
    for (int i=0;i<32;i++) xn[i] = (hx[i]-mu)*inv*s1g[i]+s1b[i];
  }

  float att[32];
  #pragma unroll
  for (int hh=0;hh<4;hh++){
    float qh[8];
    #pragma unroll
    for (int d=0;d<8;d++){
      const float4* wr = (const float4*)&swqT[hh*8+d][0];
      float a=0;
      #pragma unroll
      for (int i4=0;i4<8;i4++){
        float4 w = wr[i4];
        a += xn[4*i4+0]*w.x + xn[4*i4+1]*w.y + xn[4*i4+2]*w.z + xn[4*i4+3]*w.w;
      }
      qh[d]=a;
    }
    float ao[8];
    #pragma unroll
    for (int d=0;d<8;d++) ao[d]=0.0f;
    for (int f=0;f<64;f++){
      const float4* pm4 = (const float4*)&pmT[hh][f][0];
      float4 pa = pm4[0], pb = pm4[1];
      float qd = qh[0]*pa.x+qh[1]*pa.y+qh[2]*pa.z+qh[3]*pa.w
               + qh[4]*pb.x+qh[5]*pb.y+qh[6]*pb.z+qh[7]*pb.w;
      const float Qf = elu1_f(qd);
      const float4* kv4 = (const float4*)&kvT[hh][f][0];
      float4 va = kv4[0], vb = kv4[1];
      ao[0] += Qf*va.x; ao[1] += Qf*va.y; ao[2] += Qf*va.z; ao[3] += Qf*va.w;
      ao[4] += Qf*vb.x; ao[5] += Qf*vb.y; ao[6] += Qf*vb.z; ao[7] += Qf*vb.w;
    }
    const float den = ao[0]+ao[1]+ao[2]+ao[3]+ao[4]+ao[5]+ao[6]+ao[7];
    const float z = 1.0f/den;
    #pragma unroll
    for (int d=0;d<8;d++) att[hh*8+d] = ao[d]*z;
  }

  const float4* sbp4 = (const float4*)sbp;
  for (int o4=0;o4<8;o4++){
    float4 bb = sbp4[o4];
    float p0=bb.x, p1=bb.y, p2=bb.z, p3=bb.w;
    const float4* w0 = (const float4*)&wpT[o4*4+0][0];
    const float4* w1r= (const float4*)&wpT[o4*4+1][0];
    const float4* w2r= (const float4*)&wpT[o4*4+2][0];
    const float4* w3 = (const float4*)&wpT[o4*4+3][0];
    #pragma unroll
    for (int i4=0;i4<8;i4++){
      float4 a0=w0[i4], a1=w1r[i4], a2=w2r[i4], a3=w3[i4];
      p0 += att[4*i4+0]*a0.x + att[4*i4+1]*a0.y + att[4*i4+2]*a0.z + att[4*i4+3]*a0.w;
      p1 += att[4*i4+0]*a1.x + att[4*i4+1]*a1.y + att[4*i4+2]*a1.z + att[4*i4+3]*a1.w;
      p2 += att[4*i4+0]*a2.x + att[4*i4+1]*a2.y + att[4*i4+2]*a2.z + att[4*i4+3]*a2.w;
      p3 += att[4*i4+0]*a3.x + att[4*i4+1]*a3.y + att[4*i4+2]*a3.z + att[4*i4+3]*a3.w;
    }
    float4 hx4 = hp[o4];
    hp[o4] = make_float4(hx4.x+p0, hx4.y+p1, hx4.z+p2, hx4.w+p3);
  }
}

// ---------------------------------------------------------------------------
// Pass C2 (T=2, f16-packed weights + fdot2 — the ONLY f16 kernel, bisect):
// all f16-cast values are O(1); fp32 accumulators; no division.
// ---------------------------------------------------------------------------
__global__ __launch_bounds__(256) void k_ffn(
    float* __restrict__ hbuf,
    const float* __restrict__ ln2_g, const float* __restrict__ ln2_b,
    const float* __restrict__ w1, const float* __restrict__ b1,
    const float* __restrict__ w2, const float* __restrict__ b2, int l)
{
  __shared__ __align__(16) unsigned w1H[64][16];   // [j][i-pair]
  __shared__ __align__(16) unsigned w2H[64][16];   // [j][c-pair]
  __shared__ float s2g[32],s2b[32],sb1[64],sb2[32];
  const int tid = threadIdx.x;
  for (int idx=tid;idx<1024;idx+=256){
    int j=idx>>4, p=idx&15;
    w1H[j][p] = pk2(w1[l*2048 + (2*p)*64 + j], w1[l*2048 + (2*p+1)*64 + j]);
    w2H[j][p] = pk2(w2[l*2048 + j*32 + 2*p], w2[l*2048 + j*32 + 2*p+1]);
  }
  if (tid<32){ s2g[tid]=ln2_g[l*32+tid]; s2b[tid]=ln2_b[l*32+tid];
               sb2[tid]=b2[l*32+tid]; }
  if (tid<64) sb1[tid]=b1[l*64+tid];
  __syncthreads();

  const int tok0 = blockIdx.x*512 + tid;
  float4* hpA = (float4*)(hbuf + (size_t)tok0*32);
  float4* hpB = hpA + 256*8;

  h2 mAh[16], mBh[16];
  {
    float hx[32];
    #pragma unroll
    for (int i=0;i<8;i++){ float4 v=hpA[i]; hx[4*i]=v.x; hx[4*i+1]=v.y; hx[4*i+2]=v.z; hx[4*i+3]=v.w; }
    float mu=0;
    #pragma unroll
    for (int i=0;i<32;i++) mu += hx[i];
    mu *= (1.0f/32.0f);
    float vs=0;
    #pragma unroll
    for (int i=0;i<32;i++){ float d=hx[i]-mu; vs += d*d; }
    const float inv = rsqrtf(vs*(1.0f/32.0f)+EPS);
    #pragma unroll
    for (int p=0;p<16;p++){
      float a = (hx[2*p  ]-mu)*inv*s2g[2*p  ]+s2b[2*p  ];
      float b = (hx[2*p+1]-mu)*inv*s2g[2*p+1]+s2b[2*p+1];
      mAh[p].x=(_Float16)a; mAh[p].y=(_Float16)b;
    }
  }
  {
    float hx[32];
    #pragma unroll
    for (int i=0;i<8;i++){ float4 v=hpB[i]; hx[4*i]=v.x; hx[4*i+1]=v.y; hx[4*i+2]=v.z; hx[4*i+3]=v.w; }
    float mu=0;
    #pragma unroll
    for (int i=0;i<32;i++) mu += hx[i];
    mu *= (1.0f/32.0f);
    float vs=0;
    #pragma unroll
    for (int i=0;i<32;i++){ float d=hx[i]-mu; vs += d*d; }
    const float inv = rsqrtf(vs*(1.0f/32.0f)+EPS);
    #pragma unroll
    for (int p=0;p<16;p++){
      float a = (hx[2*p  ]-mu)*inv*s2g[2*p  ]+s2b[2*p  ];
      float b = (hx[2*p+1]-mu)*inv*s2g[2*p+1]+s2b[2*p+1];
      mBh[p].x=(_Float16)a; mBh[p].y=(_Float16)b;
    }
  }

  float fA[32], fB[32];
  #pragma unroll
  for (int c=0;c<32;c++){ fA[c]=sb2[c]; fB[c]=sb2[c]; }

  #pragma unroll 2
  for (int j=0;j<64;j++){
    const uint4* r1 = (const uint4*)&w1H[j][0];
    uint4 u0=r1[0], u1=r1[1], u2=r1[2], u3=r1[3];
    float gA = sb1[j], gB = sb1[j];
    gA=fd2(u0.x,mAh[0],gA);  gA=fd2(u0.y,mAh[1],gA);  gA=fd2(u0.z,mAh[2],gA);  gA=fd2(u0.w,mAh[3],gA);
    gA=fd2(u1.x,mAh[4],gA);  gA=fd2(u1.y,mAh[5],gA);  gA=fd2(u1.z,mAh[6],gA);  gA=fd2(u1.w,mAh[7],gA);
    gA=fd2(u2.x,mAh[8],gA);  gA=fd2(u2.y,mAh[9],gA);  gA=fd2(u2.z,mAh[10],gA); gA=fd2(u2.w,mAh[11],gA);
    gA=fd2(u3.x,mAh[12],gA); gA=fd2(u3.y,mAh[13],gA); gA=fd2(u3.z,mAh[14],gA); gA=fd2(u3.w,mAh[15],gA);
    gB=fd2(u0.x,mBh[0],gB);  gB=fd2(u0.y,mBh[1],gB);  gB=fd2(u0.z,mBh[2],gB);  gB=fd2(u0.w,mBh[3],gB);
    gB=fd2(u1.x,mBh[4],gB);  gB=fd2(u1.y,mBh[5],gB);  gB=fd2(u1.z,mBh[6],gB);  gB=fd2(u1.w,mBh[7],gB);
    gB=fd2(u2.x,mBh[8],gB);  gB=fd2(u2.y,mBh[9],gB);  gB=fd2(u2.z,mBh[10],gB); gB=fd2(u2.w,mBh[11],gB);
    gB=fd2(u3.x,mBh[12],gB); gB=fd2(u3.y,mBh[13],gB); gB=fd2(u3.z,mBh[14],gB); gB=fd2(u3.w,mBh[15],gB);
    const float ggA = gelu_f(gA);
    const float ggB = gelu_f(gB);
    const uint4* r2 = (const uint4*)&w2H[j][0];
    uint4 t0=r2[0], t1=r2[1], t2=r2[2], t3=r2[3];
    float2 c0=up2(t0.x), c1=up2(t0.y), c2=up2(t0.z), c3=up2(t0.w);
    float2 c4=up2(t1.x), c5=up2(t1.y), c6=up2(t1.z), c7=up2(t1.w);
    float2 c8=up2(t2.x), c9=up2(t2.y), c10=up2(t2.z), c11=up2(t2.w);
    float2 c12=up2(t3.x), c13=up2(t3.y), c14=up2(t3.z), c15=up2(t3.w);
    fA[0]+=ggA*c0.x;  fA[1]+=ggA*c0.y;  fA[2]+=ggA*c1.x;  fA[3]+=ggA*c1.y;
    fA[4]+=ggA*c2.x;  fA[5]+=ggA*c2.y;  fA[6]+=ggA*c3.x;  fA[7]+=ggA*c3.y;
    fA[8]+=ggA*c4.x;  fA[9]+=ggA*c4.y;  fA[10]+=ggA*c5.x; fA[11]+=ggA*c5.y;
    fA[12]+=ggA*c6.x; fA[13]+=ggA*c6.y; fA[14]+=ggA*c7.x; fA[15]+=ggA*c7.y;
    fA[16]+=ggA*c8.x; fA[17]+=ggA*c8.y; fA[18]+=ggA*c9.x; fA[19]+=ggA*c9.y;
    fA[20]+=ggA*c10.x;fA[21]+=ggA*c10.y;fA[22]+=ggA*c11.x;fA[23]+=ggA*c11.y;
    fA[24]+=ggA*c12.x;fA[25]+=ggA*c12.y;fA[26]+=ggA*c13.x;fA[27]+=ggA*c13.y;
    fA[28]+=ggA*c14.x;fA[29]+=ggA*c14.y;fA[30]+=ggA*c15.x;fA[31]+=ggA*c15.y;
    fB[0]+=ggB*c0.x;  fB[1]+=ggB*c0.y;  fB[2]+=ggB*c1.x;  fB[3]+=ggB*c1.y;
    fB[4]+=ggB*c2.x;  fB[5]+=ggB*c2.y;  fB[6]+=ggB*c3.x;  fB[7]+=ggB*c3.y;
    fB[8]+=ggB*c4.x;  fB[9]+=ggB*c4.y;  fB[10]+=ggB*c5.x; fB[11]+=ggB*c5.y;
    fB[12]+=ggB*c6.x; fB[13]+=ggB*c6.y; fB[14]+=ggB*c7.x; fB[15]+=ggB*c7.y;
    fB[16]+=ggB*c8.x; fB[17]+=ggB*c8.y; fB[18]+=ggB*c9.x; fB[19]+=ggB*c9.y;
    fB[20]+=ggB*c10.x;fB[21]+=ggB*c10.y;fB[22]+=ggB*c11.x;fB[23]+=ggB*c11.y;
    fB[24]+=ggB*c12.x;fB[25]+=ggB*c12.y;fB[26]+=ggB*c13.x;fB[27]+=ggB*c13.y;
    fB[28]+=ggB*c14.x;fB[29]+=ggB*c14.y;fB[30]+=ggB*c15.x;fB[31]+=ggB*c15.y;
  }

  #pragma unroll
  for (int o4=0;o4<8;o4++){
    float4 hA = hpA[o4];
    hpA[o4] = make_float4(hA.x+fA[4*o4+0], hA.y+fA[4*o4+1],
                          hA.z+fA[4*o4+2], hA.w+fA[4*o4+3]);
    float4 hB = hpB[o4];
    hpB[o4] = make_float4(hB.x+fB[4*o4+0], hB.y+fB[4*o4+1],
                          hB.z+fB[4*o4+2], hB.w+fB[4*o4+3]);
  }
}

// ---------------------------------------------------------------------------
// Final: layernorm -> pool score s; softmax over N per batch; weighted sum; fc
// ---------------------------------------------------------------------------
__global__ __launch_bounds__(256) void k_pool_score(
    const float* __restrict__ hbuf, const float* __restrict__ ng,
    const float* __restrict__ nb, const float* __restrict__ pw,
    const float* __restrict__ pb, float* __restrict__ s)
{
  const int tok = blockIdx.x*256 + threadIdx.x;
  float hx[32];
  const float4* src = (const float4*)(hbuf + (size_t)tok*32);
  #pragma unroll
  for (int i=0;i<8;i++){ float4 v4=src[i]; hx[4*i]=v4.x; hx[4*i+1]=v4.y; hx[4*i+2]=v4.z; hx[4*i+3]=v4.w; }
  float mu=0;
  #pragma unroll
  for (int i=0;i<32;i++) mu += hx[i];
  mu *= (1.0f/32.0f);
  float vs=0;
  #pragma unroll
  for (int i=0;i<32;i++){ float d=hx[i]-mu; vs += d*d; }
  const float inv = rsqrtf(vs*(1.0f/32.0f)+EPS);
  float sv = pb[0];
  #pragma unroll
  for (int i=0;i<32;i++) sv += ((hx[i]-mu)*inv*ng[i]+nb[i])*pw[i];
  s[tok]=sv;
}

__global__ __launch_bounds__(256) void k_softmax_stats(
    const float* __restrict__ s, float* __restrict__ bmax, float* __restrict__ bsum)
{
  __shared__ float red[256];
  __shared__ float smax_sh;
  const int b = blockIdx.x, tid = threadIdx.x;
  const float* sbp = s + (size_t)b*TOKB;
  float mx = -INFINITY;
  for (int i=tid;i<TOKB;i+=256) mx = fmaxf(mx, sbp[i]);
  red[tid]=mx; __syncthreads();
  for (int st=128;st>0;st>>=1){ if(tid<st) red[tid]=fmaxf(red[tid],red[tid+st]); __syncthreads(); }
  if (tid==0) smax_sh = red[0];
  __syncthreads();
  const float smax = smax_sh;
  float acc=0.0f;
  for (int i=tid;i<TOKB;i+=256) acc += __expf(sbp[i]-smax);
  __syncthreads();
  red[tid]=acc; __syncthreads();
  for (int st=128;st>0;st>>=1){ if(tid<st) red[tid]+=red[tid+st]; __syncthreads(); }
  if (tid==0){ bmax[b]=smax; bsum[b]=red[0]; }
}

__global__ __launch_bounds__(256) void k_pool_partial(
    const float* __restrict__ hbuf, const float* __restrict__ ng,
    const float* __restrict__ nb, const float* __restrict__ s,
    const float* __restrict__ bmax, float* __restrict__ pp)
{
  __shared__ float red[256][33];
  const int b = blockIdx.x/63, ch = blockIdx.x%63;
  const int tid = threadIdx.x;
  const int n = ch*256+tid;
  if (n < TOKB) {
    const int tok = b*TOKB+n;
    float hx[32];
    const float4* src = (const float4*)(hbuf + (size_t)tok*32);
    #pragma unroll
    for (int i=0;i<8;i++){ float4 v4=src[i]; hx[4*i]=v4.x; hx[4*i+1]=v4.y; hx[4*i+2]=v4.z; hx[4*i+3]=v4.w; }
    float mu=0;
    #pragma unroll
    for (int i=0;i<32;i++) mu += hx[i];
    mu *= (1.0f/32.0f);
    float vs=0;
    #pragma unroll
    for (int i=0;i<32;i++){ float d=hx[i]-mu; vs += d*d; }
    const float inv = rsqrtf(vs*(1.0f/32.0f)+EPS);
    const float w = __expf(s[tok]-bmax[b]);
    #pragma unroll
    for (int i=0;i<32;i++) red[tid][i] = w*((hx[i]-mu)*inv*ng[i]+nb[i]);
  } else {
    #pragma unroll
    for (int i=0;i<32;i++) red[tid][i]=0.0f;
  }
  __syncthreads();
  if (tid<32){
    float acc=0.0f;
    for (int t=0;t<256;t++) acc += red[t][tid];
    pp[(size_t)blockIdx.x*32 + tid] = acc;
  }
}

__global__ __launch_bounds__(64) void k_pool_final(
    const float* __restrict__ pp, const float* __restrict__ bsum,
    const float* __restrict__ fcw, const float* __restrict__ fcb,
    float* __restrict__ out)
{
  __shared__ float sp[32];
  const int b = blockIdx.x, tid = threadIdx.x;
  if (tid<32){
    float acc=0.0f;
    for (int ch=0;ch<63;ch++) acc += pp[(size_t)(b*63+ch)*32+tid];
    sp[tid] = acc / bsum[b];
  }
  __syncthreads();
  if (tid<2){
    float v = fcb[tid];
    for (int o=0;o<32;o++) v += sp[o]*fcw[o*2+tid];
    out[b*2+tid]=v;
  }
}

extern "C" void kernel_launch(void* const* d_in, const int* in_sizes, int n_in,
                              void* d_out, int out_size, void* d_ws, size_t ws_size,
                              hipStream_t stream)
{
  const float* x      = (const float*)d_in[0];
  const float* band_w = (const float*)d_in[1];
  const float* pw_w   = (const float*)d_in[2];
  const float* bn_g   = (const float*)d_in[3];
  const float* bn_b   = (const float*)d_in[4];
  const float* bn_m   = (const float*)d_in[5];
  const float* bn_v   = (const float*)d_in[6];
  const float* ln1_g  = (const float*)d_in[7];
  const float* ln1_b  = (const float*)d_in[8];
  const float* wqkv   = (const float*)d_in[9];
  const float* proj   = (const float*)d_in[10];
  const float* wproj  = (const float*)d_in[11];
  const float* bprojp = (const float*)d_in[12];
  const float* ln2_g  = (const float*)d_in[13];
  const float* ln2_b  = (const float*)d_in[14];
  const float* w1     = (const float*)d_in[15];
  const float* b1     = (const float*)d_in[16];
  const float* w2     = (const float*)d_in[17];
  const float* b2     = (const float*)d_in[18];
  const float* norm_g = (const float*)d_in[19];
  const float* norm_b = (const float*)d_in[20];
  const float* pool_w = (const float*)d_in[21];
  const float* pool_b = (const float*)d_in[22];
  const float* fc_w   = (const float*)d_in[23];
  const float* fc_b   = (const float*)d_in[24];
  float* out = (float*)d_out;
  float* ws  = (float*)d_ws;

  float* hbuf  = ws;                       // 8,192,000 floats (32 MB)
  float* kvp   = hbuf + 8192000;           // 2000*2048 = 4,096,000
  float* p2    = kvp  + 4096000;           // 10*2048 = 20,480
  float* KV    = p2   + 20480;             // 2048
  float* sbuf  = KV   + 2048;              // 256,000
  float* bmax  = sbuf + 256000;            // 16
  float* bsum  = bmax + 16;                // 16
  float* pp    = bsum + 16;                // 16*63*32 = 32,256

  k_tokenize<<<1024,256,0,stream>>>(x, band_w, pw_w, bn_g, bn_b, bn_m, bn_v, hbuf);
  for (int l=0;l<2;l++){
    k_kv_partial<<<2000,256,0,stream>>>(hbuf, ln1_g, ln1_b, wqkv, proj, kvp, l);
    k_kv_reduce1<<<80,256,0,stream>>>(kvp, p2);
    k_kv_reduce2<<<1,256,0,stream>>>(p2, KV);
    k_attn<<<1000,256,0,stream>>>(hbuf, ln1_g, ln1_b, wqkv, proj, wproj, bprojp, KV, l);
    k_ffn<<<500,256,0,stream>>>(hbuf, ln2_g, ln2_b, w1, b1, w2, b2, l);
  }
  k_pool_score<<<1000,256,0,stream>>>(hbuf, norm_g, norm_b, pool_w, pool_b, sbuf);
  k_softmax_stats<<<16,256,0,stream>>>(sbuf, bmax, bsum);
  k_pool_partial<<<16*63,256,0,stream>>>(hbuf, norm_g, norm_b, sbuf, bmax, pp);
  k_pool_final<<<16,64,0,stream>>>(pp, bsum, fc_w, fc_b, out);
}